// Round 11
// baseline (214.913 us; speedup 1.0000x reference)
//
#include <hip/hip_runtime.h>

#define N_NODES_C 8192
#define MAX_PATH_C 5
#define EDGE_DIM_C 32

typedef unsigned int uint4_v __attribute__((ext_vector_type(4)));

// Main zero of d_out: grid-stride 16B stores. Expected (per R1-R9 evidence)
// to run at only ~1.7 TB/s on this buffer.
__global__ void __launch_bounds__(256) k_zero_out(uint4_v* __restrict__ out, int n16)
{
    int i = blockIdx.x * blockDim.x + threadIdx.x;
    int stride = gridDim.x * blockDim.x;
    uint4_v z = (uint4_v)(0u);
    for (; i < n16; i += stride)
        out[i] = z;
}

// PROBE: identical sweep-write, but targeting 64 MiB of d_ws.
// If this hits ~7 TB/s while k_zero_out is slow -> d_out buffer property.
__global__ void __launch_bounds__(256) k_probe_ws_w(uint4_v* __restrict__ w, int n16)
{
    int i = blockIdx.x * blockDim.x + threadIdx.x;
    int stride = gridDim.x * blockDim.x;
    uint4_v z = (uint4_v)(0u);
    for (; i < n16; i += stride)
        w[i] = z;
}

// PROBE: sweep-read of the same 64 MiB (reads the zeros just written; the
// data-dependent branch keeps the loads live, condition never true).
__global__ void __launch_bounds__(256) k_probe_ws_r(
    const uint4_v* __restrict__ w, unsigned int* __restrict__ sink, int n16)
{
    int i = blockIdx.x * blockDim.x + threadIdx.x;
    int stride = gridDim.x * blockDim.x;
    unsigned int a = 0, b = 0, c = 0, d = 0;
    for (; i < n16; i += stride) {
        uint4_v v = w[i];
        a |= v[0]; b |= v[1]; c |= v[2]; d |= v[3];
    }
    if (a | b | c | d) sink[0] = a;  // never taken (region just zeroed)
}

// Pass 1: tag each touched cell with (max path index + 1) -> last-write-wins.
__global__ void __launch_bounds__(256) ee_pass1_winner(
    const int* __restrict__ src, const int* __restrict__ dst,
    unsigned int* __restrict__ outw, int P)
{
    int p = blockIdx.x * blockDim.x + threadIdx.x;
    if (p >= P) return;
    long long cell = (long long)src[p] * N_NODES_C + (long long)dst[p];
    atomicMax(outw + cell, (unsigned int)(p + 1));
}

// Pass 2: winner path replaces its tag with the encoded value.
__global__ void __launch_bounds__(256) ee_pass2_enc(
    const float* __restrict__ edge_attr,
    const float* __restrict__ edge_weights,
    const int* __restrict__ paths,
    const int* __restrict__ path_lens,
    const int* __restrict__ src, const int* __restrict__ dst,
    float* __restrict__ out, int P)
{
    __shared__ __align__(16) float w[MAX_PATH_C * EDGE_DIM_C];
    for (int i = threadIdx.x; i < MAX_PATH_C * EDGE_DIM_C; i += blockDim.x)
        w[i] = edge_weights[i];
    __syncthreads();

    int p = blockIdx.x * blockDim.x + threadIdx.x;
    if (p >= P) return;

    long long cell = (long long)src[p] * N_NODES_C + (long long)dst[p];
    const unsigned int* outw = (const unsigned int*)out;
    if (outw[cell] != (unsigned int)(p + 1)) return;  // not the last writer

    int len = path_lens[p];
    float s = 0.0f;
    #pragma unroll
    for (int l = 0; l < MAX_PATH_C; ++l) {
        if (l < len) {
            long long e = (long long)paths[p * MAX_PATH_C + l];
            const float4* __restrict__ row =
                (const float4*)(edge_attr + e * EDGE_DIM_C);
            const float4* wr = (const float4*)(w + l * EDGE_DIM_C);
            float acc = 0.0f;
            #pragma unroll
            for (int j = 0; j < EDGE_DIM_C / 4; ++j) {
                float4 a = row[j];
                float4 b = wr[j];
                acc += a.x * b.x + a.y * b.y + a.z * b.z + a.w * b.w;
            }
            s += acc;
        }
    }
    float enc = (len > 0) ? s / (float)len : 0.0f;
    if (isnan(enc)) enc = 0.0f;  // nan_to_num
    out[cell] = enc;
}

extern "C" void kernel_launch(void* const* d_in, const int* in_sizes, int n_in,
                              void* d_out, int out_size, void* d_ws, size_t ws_size,
                              hipStream_t stream)
{
    // inputs: 0:x 1:edge_attr 2:edge_weights 3:paths 4:path_lens 5:src 6:dst
    const float* edge_attr    = (const float*)d_in[1];
    const float* edge_weights = (const float*)d_in[2];
    const int*   paths        = (const int*)d_in[3];
    const int*   path_lens    = (const int*)d_in[4];
    const int*   src          = (const int*)d_in[5];
    const int*   dst          = (const int*)d_in[6];
    float* out = (float*)d_out;
    const int P = in_sizes[4];

    const int threads = 256;

    // Required: zero all of d_out (256 MB).
    int n16 = out_size / 4;
    k_zero_out<<<4096, threads, 0, stream>>>((uint4_v*)out, n16);

    // Probes: 64 MiB sweep write + read on d_ws, far from any region we use.
    // Only run if ws is large enough (harness poison shows >= 1 GiB).
    if (ws_size >= (size_t)400 * 1024 * 1024) {
        uint4_v* probe = (uint4_v*)((char*)d_ws + (size_t)256 * 1024 * 1024);
        unsigned int* sink = (unsigned int*)((char*)d_ws + (size_t)200 * 1024 * 1024);
        int pn16 = (64 * 1024 * 1024) / 16;
        k_probe_ws_w<<<1024, threads, 0, stream>>>(probe, pn16);
        k_probe_ws_r<<<1024, threads, 0, stream>>>(probe, sink, pn16);
    }

    const int pblocks = (P + threads - 1) / threads;
    ee_pass1_winner<<<pblocks, threads, 0, stream>>>(
        src, dst, (unsigned int*)out, P);
    ee_pass2_enc<<<pblocks, threads, 0, stream>>>(
        edge_attr, edge_weights, paths, path_lens, src, dst, out, P);
}

// Round 14
// 168.224 us; speedup vs baseline: 1.2775x; 1.2775x over previous
//
#include <hip/hip_runtime.h>

#define N_NODES_C 8192
#define MAX_PATH_C 5
#define EDGE_DIM_C 32

// Structure (R1 champion, best of 6 variants tried in R1-R11):
//   d_out bulk traffic is capped at ~1.7 TB/s in BOTH directions regardless
//   of method (rocclr fill / plain dwordx4 / NT stores / LDS-staged rows /
//   conditional read+write), while identical kernels hit ~7 TB/s on d_ws.
//   => buffer property of d_out. Mandatory cost: one 256 MB define of d_out
//   ~= 155 us. Scattered hot-line ops on d_out are fast (~6-11 us), so:
//   memset (fastest capped writer) + scatter passes = ~168 us floor.
__global__ void __launch_bounds__(256) ee_pass1_winner(
    const int* __restrict__ src, const int* __restrict__ dst,
    unsigned int* __restrict__ outw, int P)
{
    int p = blockIdx.x * blockDim.x + threadIdx.x;
    if (p >= P) return;
    long long cell = (long long)src[p] * N_NODES_C + (long long)dst[p];
    atomicMax(outw + cell, (unsigned int)(p + 1));  // numpy last-write-wins
}

__global__ void __launch_bounds__(256) ee_pass2_enc(
    const float* __restrict__ edge_attr,
    const float* __restrict__ edge_weights,
    const int* __restrict__ paths,
    const int* __restrict__ path_lens,
    const int* __restrict__ src, const int* __restrict__ dst,
    float* __restrict__ out, int P)
{
    __shared__ __align__(16) float w[MAX_PATH_C * EDGE_DIM_C];
    for (int i = threadIdx.x; i < MAX_PATH_C * EDGE_DIM_C; i += blockDim.x)
        w[i] = edge_weights[i];
    __syncthreads();

    int p = blockIdx.x * blockDim.x + threadIdx.x;
    if (p >= P) return;

    long long cell = (long long)src[p] * N_NODES_C + (long long)dst[p];
    const unsigned int* outw = (const unsigned int*)out;
    if (outw[cell] != (unsigned int)(p + 1)) return;  // not the last writer

    int len = path_lens[p];
    float s = 0.0f;
    #pragma unroll
    for (int l = 0; l < MAX_PATH_C; ++l) {
        if (l < len) {
            long long e = (long long)paths[p * MAX_PATH_C + l];
            const float4* __restrict__ row =
                (const float4*)(edge_attr + e * EDGE_DIM_C);
            const float4* wr = (const float4*)(w + l * EDGE_DIM_C);
            float acc = 0.0f;
            #pragma unroll
            for (int j = 0; j < EDGE_DIM_C / 4; ++j) {
                float4 a = row[j];
                float4 b = wr[j];
                acc += a.x * b.x + a.y * b.y + a.z * b.z + a.w * b.w;
            }
            s += acc;
        }
    }
    float enc = (len > 0) ? s / (float)len : 0.0f;
    if (isnan(enc)) enc = 0.0f;  // nan_to_num
    out[cell] = enc;
}

extern "C" void kernel_launch(void* const* d_in, const int* in_sizes, int n_in,
                              void* d_out, int out_size, void* d_ws, size_t ws_size,
                              hipStream_t stream)
{
    // inputs: 0:x 1:edge_attr 2:edge_weights 3:paths 4:path_lens 5:src 6:dst
    const float* edge_attr    = (const float*)d_in[1];
    const float* edge_weights = (const float*)d_in[2];
    const int*   paths        = (const int*)d_in[3];
    const int*   path_lens    = (const int*)d_in[4];
    const int*   src          = (const int*)d_in[5];
    const int*   dst          = (const int*)d_in[6];
    float* out = (float*)d_out;
    const int P = in_sizes[4];

    hipMemsetAsync(d_out, 0, (size_t)out_size * sizeof(float), stream);

    const int threads = 256;
    const int blocks = (P + threads - 1) / threads;
    ee_pass1_winner<<<blocks, threads, 0, stream>>>(
        src, dst, (unsigned int*)out, P);
    ee_pass2_enc<<<blocks, threads, 0, stream>>>(
        edge_attr, edge_weights, paths, path_lens, src, dst, out, P);
}